// Round 6
// baseline (207.758 us; speedup 1.0000x reference)
//
#include <hip/hip_runtime.h>
#include <math.h>

#define N_PRED  12
#define N_DRIFT 2
#define N_DW    3
#define N_NODES 4096
#define BB      128
#define LL      16
#define BN      (BB * N_NODES)   // 524288 pairs
#define TPB     128              // 2 waves per block
#define CPW     8                // chunks per wave (64 pairs each)
#define NBLK    512              // 1024 waves x 8 chunks = 8192 chunks, no tail

// ---------------------------------------------------------------------------
// Pre-kernel: fold (deform ∘ conv_t) and (deform ∘ conv_n) into dense uniform
// matrices Mt, Mn of shape [48][12]. Unchanged (verified correct).
// ---------------------------------------------------------------------------
__global__ void deform_precompute(const float* __restrict__ offset_t,
                                  const float* __restrict__ offset_n,
                                  const float* __restrict__ conv_t_w,
                                  const float* __restrict__ conv_n_w,
                                  float* __restrict__ Mt,
                                  float* __restrict__ Mn) {
    int t = threadIdx.x;
    if (t >= N_PRED * N_DW * LL) return;      // 576
    int q  = t % N_PRED;
    int kl = t / N_PRED;
    int k  = kl / LL;
    int l  = kl % LL;

    auto coef = [&](const float* off, int c) -> float {
        float pos = tanhf(off[k * N_PRED + c]) * (float)N_DRIFT
                    + (float)(c + N_DRIFT);
        float idf = floorf(pos);
        float fr  = pos - idf;
        int   id  = (int)idf;
        if (l == id)     return 1.0f - fr;
        if (l == id + 1) return fr;
        return 0.0f;
    };

    float mt = 0.0f;
    #pragma unroll
    for (int h = 0; h < 3; ++h) {
        int c = q - 1 + h;
        if (c < 0 || c >= N_PRED) continue;
        mt += conv_t_w[k * 3 + h] * coef(offset_t, c);
    }

    float mn = 0.0f;
    #pragma unroll
    for (int c = 0; c < N_PRED; ++c) {
        mn += conv_n_w[q * (N_PRED * N_DW) + c * N_DW + k] * coef(offset_n, c);
    }

    Mt[kl * N_PRED + q] = mt;
    Mn[kl * N_PRED + q] = mn;
}

// ---------------------------------------------------------------------------
// Main kernel, R8: persistent wave-private double-buffered global_load_lds
// pipeline. Fusion of the two HW-verified halves:
//   R7 (61us): wave-private everything, zero barriers, clean IO  [kept]
//   R5: gll staging + counted-vmcnt pipeline mechanism verified  [kept]
// minus both proven failure modes:
//   - NO reg-held prefetch (R4/R6: spills at >~50 live VGPRs)
//   - NO swizzled gll source (R5: TA decoalesce) -> XROW=12 LINEAR layout;
//     the stride-12 ds_read_b128 4-way bank conflict costs ~80cy/chunk
//     (m136: 1.58x on 12 reads) vs a ~7K cy chunk period: accepted.
//   - NO "memory" clobbers in the loop (R5: forced uniform rematerialization)
//
// Per wave: 8 consecutive chunks of 64 pairs. Iteration k:
//   [bparam 3 reg-loads (chunk k)] [15 gll: stage chunk k+1 into buf^1]
//   s_waitcnt vmcnt(18)   // 18 newest = 3 bv + 15 gll; in-order retirement
//                         // => chunk k's 15 gll (issued last iter) complete
//   compute chunk k from buf | os4 restage | 3x 1KB coalesced stores
// sched_barrier(0) walls pin issue order (m201 template discipline).
// LDS 67584 B -> 2 blocks/CU; grid 512 = exactly 2/CU, persistent, no tail.
// Latency hidden by the pipeline, not TLP: ~15KB always in flight per wave.
// ---------------------------------------------------------------------------
typedef const __attribute__((address_space(1))) void* gas1_t;
typedef __attribute__((address_space(3))) void* las3_t;

__device__ __forceinline__ void gll16(const void* g, void* lds) {
    __builtin_amdgcn_global_load_lds((gas1_t)g, (las3_t)lds, 16, 0, 0);
}

__global__ __launch_bounds__(TPB, 1) void deform_main(
        const float* __restrict__ inp,      // (BN, 3, 16)
        const float* __restrict__ ctrl,     // (BN, 12)
        const float* __restrict__ W,        // (12, 12)
        const float* __restrict__ bparam,   // (N_NODES, 12)
        const float* __restrict__ conv_t_b, // (1,)
        const float* __restrict__ conv_n_b, // (12,)
        const float* __restrict__ Mt,       // (48, 12)
        const float* __restrict__ Mn,       // (48, 12)
        float* __restrict__ out) {          // (BN, 12)
    __shared__ float4 xs4[2][2][768];       // [buf][wave][slot] 49152 B
    __shared__ float4 cs4[2][2][192];       // [buf][wave][slot] 12288 B
    __shared__ float4 os4[2][192];          // [wave][slot]       6144 B

    const int t  = threadIdx.x;
    const int l  = t & 63;                  // lane
    const int w  = t >> 6;                  // wave (0/1)
    const int gw = blockIdx.x * 2 + w;      // global wave id, 0..1023
    const int cbase = gw * CPW;             // first chunk of this wave

    const char* gx = (const char*)inp;      // 12288 B per chunk (64 pairs)
    const char* gc = (const char*)ctrl;     //  3072 B per chunk

    // stage chunk c into buffer b: 15 gll, linear source, linear LDS dest
    // (gll HW: wave-uniform LDS base + lane*16; global addr per-lane)
    auto STAGE = [&](int b, int c) {
        const char* sx = gx + (size_t)c * 12288 + (size_t)l * 16;
        #pragma unroll
        for (int j = 0; j < 12; ++j)
            gll16(sx + j * 1024, &xs4[b][w][j * 64]);
        const char* sc = gc + (size_t)c * 3072 + (size_t)l * 16;
        #pragma unroll
        for (int j = 0; j < 3; ++j)
            gll16(sc + j * 1024, &cs4[b][w][j * 64]);
    };

    // prologue: stage chunk 0 into buf 0 (wait happens inside iter 0)
    STAGE(0, cbase);

    const float ctb = conv_t_b[0];

    #pragma unroll 1
    for (int k = 0; k < CPW; ++k) {
        const int b = k & 1;
        const int c = cbase + k;

        __builtin_amdgcn_sched_barrier(0);
        // ---- bparam row for this chunk: 3 reg loads (L2-resident 192 KB),
        //      issued BEFORE the stage so the vmcnt count below is exact ----
        float4 bv0, bv1, bv2;
        {
            const int n = ((c & 63) << 6) + l;          // (c*64+l) & 4095
            const float4* gbp = (const float4*)bparam + (size_t)n * 3;
            bv0 = gbp[0]; bv1 = gbp[1]; bv2 = gbp[2];
        }
        __builtin_amdgcn_sched_barrier(0);
        // ---- issue next chunk's 15 gll (double buffer) ----
        if (k + 1 < CPW) STAGE(b ^ 1, c + 1);
        __builtin_amdgcn_sched_barrier(0);
        // ---- counted wait: drain everything older than [3 bv + 15 gll]
        //      = chunk k's staging (and last iter's stores). Last iter has
        //      no stage -> full drain (one-time ~600cy, negligible). ----
        if (k + 1 < CPW) asm volatile("s_waitcnt vmcnt(18)");
        else             asm volatile("s_waitcnt vmcnt(0)");
        __builtin_amdgcn_sched_barrier(0);

        // ---- pred_t / pred_n accumulators (biases) ----
        float acct[12], accn[12];
        #pragma unroll
        for (int q = 0; q < N_PRED; ++q) {
            acct[q] = ctb;
            accn[q] = conv_n_b[q];
        }

        // ---- folded matvecs: 1152 FMAs, weights wave-uniform (s_load);
        //      x row = linear slots l*12+cc (4-way quad conflict, accepted) --
        #pragma unroll
        for (int cc = 0; cc < 12; ++cc) {
            float4 v = xs4[b][w][l * 12 + cc];
            #pragma unroll
            for (int e = 0; e < 4; ++e) {
                float xv = (e == 0) ? v.x : (e == 1) ? v.y : (e == 2) ? v.z : v.w;
                const int kl = 4 * cc + e;
                #pragma unroll
                for (int q = 0; q < N_PRED; ++q) {
                    acct[q] = fmaf(Mt[kl * N_PRED + q], xv, acct[q]);
                    accn[q] = fmaf(Mn[kl * N_PRED + q], xv, accn[q]);
                }
            }
        }

        // ---- gate matvec: ctrl from LDS (stride-3: conflict-free) ----
        float accg[12];
        {
            const float* bvf0 = (const float*)&bv0;
            const float* bvf1 = (const float*)&bv1;
            const float* bvf2 = (const float*)&bv2;
            #pragma unroll
            for (int i = 0; i < 4; ++i) {
                accg[i]     = bvf0[i];
                accg[4 + i] = bvf1[i];
                accg[8 + i] = bvf2[i];
            }
        }
        float cr[12];
        #pragma unroll
        for (int i = 0; i < 3; ++i) {
            float4 v = cs4[b][w][l * 3 + i];
            cr[4 * i + 0] = v.x; cr[4 * i + 1] = v.y;
            cr[4 * i + 2] = v.z; cr[4 * i + 3] = v.w;
        }
        #pragma unroll
        for (int p = 0; p < N_PRED; ++p) {
            float cv = cr[p];
            #pragma unroll
            for (int q = 0; q < N_PRED; ++q) {
                accg[q] = fmaf(cv, W[p * N_PRED + q], accg[q]);
            }
        }

        // ---- sigmoid gate + blend ----
        float4 o4[3];
        float* ov = (float*)o4;
        #pragma unroll
        for (int q = 0; q < N_PRED; ++q) {
            float g = 1.0f / (1.0f + __expf(-accg[q]));
            ov[q] = accn[q] * g + acct[q] * (1.0f - g);
        }

        // ---- wave-private output restage (same-wave DS is in-order) ----
        #pragma unroll
        for (int j = 0; j < 3; ++j) {
            os4[w][3 * l + j] = o4[j];       // quads 3l+j: conflict-free
        }
        // ---- fully-coalesced 1 KB stores ----
        float4* gout = (float4*)out + (size_t)c * 192;
        #pragma unroll
        for (int j = 0; j < 3; ++j) {
            int s = j * 64 + l;
            gout[s] = os4[w][s];
        }
        __builtin_amdgcn_sched_barrier(0);
    }
}

extern "C" void kernel_launch(void* const* d_in, const int* in_sizes, int n_in,
                              void* d_out, int out_size, void* d_ws, size_t ws_size,
                              hipStream_t stream) {
    const float* inp      = (const float*)d_in[0];
    const float* ctrl     = (const float*)d_in[1];
    const float* offset_t = (const float*)d_in[2];
    const float* offset_n = (const float*)d_in[3];
    const float* conv_t_w = (const float*)d_in[4];
    const float* conv_t_b = (const float*)d_in[5];
    const float* conv_n_w = (const float*)d_in[6];
    const float* conv_n_b = (const float*)d_in[7];
    const float* W        = (const float*)d_in[8];
    const float* bparam   = (const float*)d_in[9];
    float* out = (float*)d_out;

    float* Mt = (float*)d_ws;            // 576 floats
    float* Mn = Mt + N_DW * LL * N_PRED; // 576 floats (ws >= 4608 B)

    deform_precompute<<<1, 576, 0, stream>>>(offset_t, offset_n,
                                             conv_t_w, conv_n_w, Mt, Mn);
    deform_main<<<NBLK, TPB, 0, stream>>>(inp, ctrl, W, bparam,
                                          conv_t_b, conv_n_b, Mt, Mn, out);
}